// Round 4
// baseline (736.831 us; speedup 1.0000x reference)
//
#include <hip/hip_runtime.h>
#include <hip/hip_bf16.h>
#include <stdint.h>

#define B_SZ 8192
#define D_SZ 1024
#define O_SZ 1024
#define E_SZ 8

#define BM 256
#define BN 128
#define BK 64
#define NT 128  // virtual K-steps: E_SZ * (D_SZ / BK)

typedef __bf16 bf16_t;
typedef __bf16 bf16x8 __attribute__((ext_vector_type(8)));
typedef __bf16 bf16x4 __attribute__((ext_vector_type(4)));
typedef float  f32x4  __attribute__((ext_vector_type(4)));

// ---------------- merged prep: gating+cvt (blocks 0..2047) | We transpose (2048..4095) ----------------
__global__ __launch_bounds__(256) void prep_kernel(
    const float* __restrict__ x, const float* __restrict__ Wg,
    const float* __restrict__ bg, const float* __restrict__ We,
    float* __restrict__ gates, bf16_t* __restrict__ xb,
    bf16_t* __restrict__ wet) {
  __shared__ float tile[64][65];
  const int bid = blockIdx.x;
  if (bid < 2048) {
    // ---- gating: softmax(x @ Wg + bg) fused with x fp32->bf16 ----
    const int w = threadIdx.x >> 6, lane = threadIdx.x & 63;
    const int b = bid * 4 + w;
    const float4* xr = (const float4*)(x + (size_t)b * D_SZ);
    bf16x4* xbr = (bf16x4*)(xb + (size_t)b * D_SZ);
    float acc[8];
#pragma unroll
    for (int e = 0; e < 8; ++e) acc[e] = 0.f;
#pragma unroll 1
    for (int it = 0; it < 4; ++it) {
      int d4 = it * 64 + lane;  // float4 index; d = d4*4
      float4 v = xr[d4];
      bf16x4 ob;
      ob[0] = (bf16_t)v.x; ob[1] = (bf16_t)v.y;
      ob[2] = (bf16_t)v.z; ob[3] = (bf16_t)v.w;
      xbr[d4] = ob;
      const float4* wr = (const float4*)(Wg + (size_t)d4 * 32);  // 4 rows x 8
      float xs[4] = {v.x, v.y, v.z, v.w};
#pragma unroll
      for (int rr = 0; rr < 4; ++rr) {
        float4 wa = wr[rr * 2], wb = wr[rr * 2 + 1];
        acc[0] += xs[rr] * wa.x; acc[1] += xs[rr] * wa.y;
        acc[2] += xs[rr] * wa.z; acc[3] += xs[rr] * wa.w;
        acc[4] += xs[rr] * wb.x; acc[5] += xs[rr] * wb.y;
        acc[6] += xs[rr] * wb.z; acc[7] += xs[rr] * wb.w;
      }
    }
#pragma unroll
    for (int off = 32; off >= 1; off >>= 1) {
#pragma unroll
      for (int e = 0; e < 8; ++e) acc[e] += __shfl_xor(acc[e], off, 64);
    }
    if (lane == 0) {
#pragma unroll
      for (int e = 0; e < 8; ++e) acc[e] += bg[e];
      float m = acc[0];
#pragma unroll
      for (int e = 1; e < 8; ++e) m = fmaxf(m, acc[e]);
      float s = 0.f, ex[8];
#pragma unroll
      for (int e = 0; e < 8; ++e) { ex[e] = __expf(acc[e] - m); s += ex[e]; }
      float inv = 1.0f / s;
      float* gr = gates + (size_t)b * 8;
#pragma unroll
      for (int e = 0; e < 8; ++e) gr[e] = ex[e] * inv;
    }
  } else {
    // ---- We [E,D,O] fp32 -> WeT [E,O,D] bf16 ----
    const int bt = bid - 2048;
    const int e = bt >> 8;
    const int d0 = ((bt >> 4) & 15) * 64, o0 = (bt & 15) * 64;
    const int tx = threadIdx.x & 63, ty = threadIdx.x >> 6;
    const float* src = We + (size_t)e * D_SZ * O_SZ;
#pragma unroll
    for (int i = 0; i < 16; ++i) {
      int d = ty + i * 4;
      tile[d][tx] = src[(size_t)(d0 + d) * O_SZ + o0 + tx];
    }
    __syncthreads();
    bf16_t* dst = wet + (size_t)e * O_SZ * D_SZ;
#pragma unroll
    for (int i = 0; i < 16; ++i) {
      int o = ty + i * 4;
      dst[(size_t)(o0 + o) * D_SZ + d0 + tx] = (bf16_t)tile[tx][o];
    }
  }
}

// ---------------- fused expert GEMM + gate combine ----------------
// 4 waves x (64M x 128N) wave-tiles: LDS reads/step drop 128->96 b128
// (port 1920->1536 cyc); 1 wave/SIMD with full VGPR budget.
__device__ __forceinline__ void gl16(const bf16_t* g, const bf16_t* l) {
  __builtin_amdgcn_global_load_lds(
      (const __attribute__((address_space(1))) void*)g,
      (__attribute__((address_space(3))) void*)l, 16, 0, 0);
}

__global__ __launch_bounds__(256, 1) void moe_gemm(
    const bf16_t* __restrict__ xb,    // [B, D] bf16
    const bf16_t* __restrict__ wet,   // [E, O, D] bf16
    const float* __restrict__ gates,  // [B, E]
    const float* __restrict__ be,     // [E, O]
    float* __restrict__ out)          // [B, O]
{
  // ring-3 buffers: compute t from buf t%3, stage t+2 into (t+2)%3
  __shared__ bf16_t lA[3][BM * BK];   // 3 x 32 KB
  __shared__ bf16_t lB[3][BN * BK];   // 3 x 16 KB
  __shared__ float  lG[BM * 9];       // gates, padded stride 9
  __shared__ float  lBe[E_SZ * BN];   // be tile

  const int tid = threadIdx.x;
  const int w = tid >> 6, lane = tid & 63;

  // ---- XCD-locality remap (round 2: FETCH 533->97 MB) ----
  const int flat = blockIdx.x + (blockIdx.y << 3);  // gridDim.x == 8
  const int xcd = flat & 7, slot = flat >> 3;
  const int bt = (xcd << 2) + (slot & 3);  // b-tile 0..31
  const int ot = slot >> 2;                // o-tile 0..7
  const int b0 = bt * BM;
  const int o0 = ot * BN;

  const int wm = w * 64;                   // wave-tile: rows [wm, wm+64), cols [0,128)
  const int m16 = lane & 15, q = lane >> 4;

  // ---- prologue: gates + be into LDS ----
  {
#pragma unroll
    for (int p = 0; p < 2; ++p) {
      int idx = tid + 256 * p;             // 512 f32x4 = 256 rows x 8 gates
      float4 g4 = ((const float4*)(gates + (size_t)b0 * 8))[idx];
      int gr = idx >> 1, gc = (idx & 1) * 4;
      lG[gr * 9 + gc + 0] = g4.x; lG[gr * 9 + gc + 1] = g4.y;
      lG[gr * 9 + gc + 2] = g4.z; lG[gr * 9 + gc + 3] = g4.w;
    }
#pragma unroll
    for (int p = 0; p < 4; ++p) {
      int idx = tid + 256 * p;
      lBe[idx] = be[(size_t)(idx >> 7) * O_SZ + o0 + (idx & 127)];
    }
  }

  // ---- per-lane staging constants ----
  // LDS dest linear (wave base + lane*16); swizzle on the GLOBAL side:
  // phys 16B slot s at row r holds logical slot s^(r&7); read applies same XOR.
  const bf16_t* aptr[8]; int aoffL[8];
#pragma unroll
  for (int j = 0; j < 8; ++j) {
    int g0 = w * 64 + 256 * j;            // wave-uniform base granule (A: 2048 granules)
    int row = (g0 >> 3) + (lane >> 3);    // 8 granules (128B) per 64-col row
    int ls = (lane & 7) ^ (row & 7);
    aptr[j] = xb + (size_t)(b0 + row) * D_SZ + ls * 8;
    aoffL[j] = g0 * 8;                    // LDS elem offset
  }
  const bf16_t* bptr[4]; int boffL[4];
#pragma unroll
  for (int j = 0; j < 4; ++j) {
    int g0 = w * 64 + 256 * j;            // B: 1024 granules
    int row = (g0 >> 3) + (lane >> 3);
    int ls = (lane & 7) ^ (row & 7);
    bptr[j] = wet + (size_t)(o0 + row) * D_SZ + ls * 8;
    boffL[j] = g0 * 8;
  }

  // ---- hoisted per-lane LDS read byte-offsets ----
  const int xk = m16 & 7;
  const int offA0 = (wm + m16) * 128 + ((q ^ xk) << 4);
  const int offA1 = (wm + m16) * 128 + (((4 | q) ^ xk) << 4);
  const int offB0 = m16 * 128 + ((q ^ xk) << 4);
  const int offB1 = m16 * 128 + (((4 | q) ^ xk) << 4);

#define STAGE(t_, buf_) do {                                                   \
    const int kk_ = ((t_) & 15) << 6;                                          \
    const size_t eo_ = (((size_t)((t_) >> 4)) << 20) + kk_;                    \
    _Pragma("unroll")                                                          \
    for (int js = 0; js < 8; ++js) gl16(aptr[js] + kk_, &lA[buf_][0] + aoffL[js]); \
    _Pragma("unroll")                                                          \
    for (int js = 0; js < 4; ++js) gl16(bptr[js] + eo_, &lB[buf_][0] + boffL[js]); \
  } while (0)

  f32x4 acc[4][8], outAcc[4][8];
#pragma unroll
  for (int i = 0; i < 4; ++i)
#pragma unroll
    for (int j = 0; j < 8; ++j) {
      acc[i][j] = f32x4{0.f, 0.f, 0.f, 0.f};
      outAcc[i][j] = f32x4{0.f, 0.f, 0.f, 0.f};
    }

  STAGE(0, 0);
  STAGE(1, 1);
  // drain own lG/lBe ds_writes so the first loop barrier publishes them
  asm volatile("s_waitcnt lgkmcnt(0)" ::: "memory");

  // one k-half: 8 B-reads + 4 A-reads -> 32 MFMA under setprio
#define HALF(cur_, OA_, OB_) do {                                              \
    const char* la_ = (const char*)(&lA[cur_][0]);                             \
    const char* lb_ = (const char*)(&lB[cur_][0]);                             \
    bf16x8 a_[4], b_[8];                                                       \
    _Pragma("unroll")                                                          \
    for (int j = 0; j < 8; ++j) b_[j] = *(const bf16x8*)(lb_ + (OB_) + j * 2048); \
    _Pragma("unroll")                                                          \
    for (int i = 0; i < 4; ++i) a_[i] = *(const bf16x8*)(la_ + (OA_) + i * 2048); \
    __builtin_amdgcn_s_setprio(1);                                             \
    _Pragma("unroll")                                                          \
    for (int i = 0; i < 4; ++i)                                                \
      _Pragma("unroll")                                                        \
      for (int j = 0; j < 8; ++j)                                              \
        acc[i][j] = __builtin_amdgcn_mfma_f32_16x16x32_bf16(                   \
            a_[i], b_[j], acc[i][j], 0, 0, 0);                                 \
    __builtin_amdgcn_s_setprio(0);                                             \
  } while (0)

  // wave-parity stagger: even waves half0->half1, odd waves half1->half0,
  // so LDS-read and MFMA phases interleave across SIMDs instead of bursting.
#define BODY(cur_) do {                                                        \
    if ((w & 1) == 0) {                                                        \
      HALF(cur_, offA0, offB0);                                                \
      HALF(cur_, offA1, offB1);                                                \
    } else {                                                                   \
      HALF(cur_, offA1, offB1);                                                \
      HALF(cur_, offA0, offB0);                                                \
    }                                                                          \
  } while (0)

  // C layout: col = lane&15, row = q*4+reg
#define COMBINE(e_) do {                                                       \
    float bec_[8];                                                             \
    _Pragma("unroll")                                                          \
    for (int j = 0; j < 8; ++j) bec_[j] = lBe[(e_) * BN + j * 16 + m16];       \
    _Pragma("unroll")                                                          \
    for (int i = 0; i < 4; ++i) {                                              \
      _Pragma("unroll")                                                        \
      for (int rg = 0; rg < 4; ++rg) {                                         \
        float gv = lG[(wm + i * 16 + q * 4 + rg) * 9 + (e_)];                  \
        _Pragma("unroll")                                                      \
        for (int j = 0; j < 8; ++j) {                                          \
          outAcc[i][j][rg] += gv * (acc[i][j][rg] + bec_[j]);                  \
          acc[i][j][rg] = 0.f;                                                 \
        }                                                                      \
      }                                                                        \
    }                                                                          \
  } while (0)

  // one K-step; 12 loads/wave/stage -> steady-state wait vmcnt(12)
#define STEP_S(t_, cur_, nb_) do {                                             \
    asm volatile("s_waitcnt vmcnt(12)" ::: "memory");                          \
    __builtin_amdgcn_s_barrier();                                              \
    asm volatile("" ::: "memory");                                             \
    STAGE((t_) + 2, nb_);                                                      \
    BODY(cur_);                                                                \
    if (((t_) & 15) == 15) COMBINE((t_) >> 4);                                 \
  } while (0)

#pragma unroll 1
  for (int t3 = 0; t3 < 126; t3 += 3) {
    STEP_S(t3 + 0, 0, 2);
    STEP_S(t3 + 1, 1, 0);
    STEP_S(t3 + 2, 2, 1);
  }
  // t = 126: no stage (tiles 0..127 all staged)
  asm volatile("s_waitcnt vmcnt(12)" ::: "memory");
  __builtin_amdgcn_s_barrier();
  asm volatile("" ::: "memory");
  BODY(0);
  // t = 127: final tile in buf 1
  asm volatile("s_waitcnt vmcnt(0)" ::: "memory");
  __builtin_amdgcn_s_barrier();
  asm volatile("" ::: "memory");
  BODY(1);
  COMBINE(7);

  // ---- epilogue: store combined output ----
#pragma unroll
  for (int i = 0; i < 4; ++i)
#pragma unroll
    for (int rg = 0; rg < 4; ++rg) {
      float* orow = out + (size_t)(b0 + wm + i * 16 + q * 4 + rg) * O_SZ
                    + o0 + m16;
#pragma unroll
      for (int j = 0; j < 8; ++j) orow[j * 16] = outAcc[i][j][rg];
    }
}

extern "C" void kernel_launch(void* const* d_in, const int* in_sizes, int n_in,
                              void* d_out, int out_size, void* d_ws, size_t ws_size,
                              hipStream_t stream) {
  const float* x  = (const float*)d_in[0];
  const float* Wg = (const float*)d_in[1];
  const float* bg = (const float*)d_in[2];
  const float* We = (const float*)d_in[3];
  const float* be = (const float*)d_in[4];
  float* out = (float*)d_out;

  char* ws = (char*)d_ws;
  float*  gates = (float*)ws;                             // 256 KB
  bf16_t* xb    = (bf16_t*)(ws + (1 << 18));              // 16 MB
  bf16_t* wet   = (bf16_t*)(ws + (1 << 18) + (1 << 24));  // 16 MB

  prep_kernel<<<4096, 256, 0, stream>>>(x, Wg, bg, We, gates, xb, wet);
  moe_gemm<<<dim3(O_SZ / BN, B_SZ / BM), 256, 0, stream>>>(xb, wet, gates, be, out);
}

// Round 5
// 403.329 us; speedup vs baseline: 1.8269x; 1.8269x over previous
//
#include <hip/hip_runtime.h>
#include <hip/hip_bf16.h>
#include <stdint.h>

#define B_SZ 8192
#define D_SZ 1024
#define O_SZ 1024
#define E_SZ 8

#define BM 256
#define BN 128
#define BK 64
#define NT 128  // virtual K-steps: E_SZ * (D_SZ / BK)

typedef __bf16 bf16_t;
typedef __bf16 bf16x8 __attribute__((ext_vector_type(8)));
typedef __bf16 bf16x4 __attribute__((ext_vector_type(4)));
typedef float  f32x4  __attribute__((ext_vector_type(4)));

// ---------------- merged prep: gating+cvt (blocks 0..2047) | We transpose (2048..4095) ----------------
__global__ __launch_bounds__(256) void prep_kernel(
    const float* __restrict__ x, const float* __restrict__ Wg,
    const float* __restrict__ bg, const float* __restrict__ We,
    float* __restrict__ gates, bf16_t* __restrict__ xb,
    bf16_t* __restrict__ wet) {
  __shared__ float tile[64][65];
  const int bid = blockIdx.x;
  if (bid < 2048) {
    // ---- gating: softmax(x @ Wg + bg) fused with x fp32->bf16 ----
    const int w = threadIdx.x >> 6, lane = threadIdx.x & 63;
    const int b = bid * 4 + w;
    const float4* xr = (const float4*)(x + (size_t)b * D_SZ);
    bf16x4* xbr = (bf16x4*)(xb + (size_t)b * D_SZ);
    float acc[8];
#pragma unroll
    for (int e = 0; e < 8; ++e) acc[e] = 0.f;
#pragma unroll 1
    for (int it = 0; it < 4; ++it) {
      int d4 = it * 64 + lane;  // float4 index; d = d4*4
      float4 v = xr[d4];
      bf16x4 ob;
      ob[0] = (bf16_t)v.x; ob[1] = (bf16_t)v.y;
      ob[2] = (bf16_t)v.z; ob[3] = (bf16_t)v.w;
      xbr[d4] = ob;
      const float4* wr = (const float4*)(Wg + (size_t)d4 * 32);  // 4 rows x 8
      float xs[4] = {v.x, v.y, v.z, v.w};
#pragma unroll
      for (int rr = 0; rr < 4; ++rr) {
        float4 wa = wr[rr * 2], wb = wr[rr * 2 + 1];
        acc[0] += xs[rr] * wa.x; acc[1] += xs[rr] * wa.y;
        acc[2] += xs[rr] * wa.z; acc[3] += xs[rr] * wa.w;
        acc[4] += xs[rr] * wb.x; acc[5] += xs[rr] * wb.y;
        acc[6] += xs[rr] * wb.z; acc[7] += xs[rr] * wb.w;
      }
    }
#pragma unroll
    for (int off = 32; off >= 1; off >>= 1) {
#pragma unroll
      for (int e = 0; e < 8; ++e) acc[e] += __shfl_xor(acc[e], off, 64);
    }
    if (lane == 0) {
#pragma unroll
      for (int e = 0; e < 8; ++e) acc[e] += bg[e];
      float m = acc[0];
#pragma unroll
      for (int e = 1; e < 8; ++e) m = fmaxf(m, acc[e]);
      float s = 0.f, ex[8];
#pragma unroll
      for (int e = 0; e < 8; ++e) { ex[e] = __expf(acc[e] - m); s += ex[e]; }
      float inv = 1.0f / s;
      float* gr = gates + (size_t)b * 8;
#pragma unroll
      for (int e = 0; e < 8; ++e) gr[e] = ex[e] * inv;
    }
  } else {
    // ---- We [E,D,O] fp32 -> WeT [E,O,D] bf16 ----
    const int bt = bid - 2048;
    const int e = bt >> 8;
    const int d0 = ((bt >> 4) & 15) * 64, o0 = (bt & 15) * 64;
    const int tx = threadIdx.x & 63, ty = threadIdx.x >> 6;
    const float* src = We + (size_t)e * D_SZ * O_SZ;
#pragma unroll
    for (int i = 0; i < 16; ++i) {
      int d = ty + i * 4;
      tile[d][tx] = src[(size_t)(d0 + d) * O_SZ + o0 + tx];
    }
    __syncthreads();
    bf16_t* dst = wet + (size_t)e * O_SZ * D_SZ;
#pragma unroll
    for (int i = 0; i < 16; ++i) {
      int o = ty + i * 4;
      dst[(size_t)(o0 + o) * D_SZ + d0 + tx] = (bf16_t)tile[tx][o];
    }
  }
}

// ---------------- fused expert GEMM, Horner gate-folding, K-split wave pairs ----------------
// 8 waves; wave w: output tile 128x64 at (mrow,ncol), K-half kh = w&1.
// Horner: acc = (acc + be_e) * (g_e/g_{e+1}) at each expert boundary; no outAcc.
// Pairs (w, w^1) hold K-partials of the same tile; single reduce at the end.
__device__ __forceinline__ void gl16(const bf16_t* g, const bf16_t* l) {
  __builtin_amdgcn_global_load_lds(
      (const __attribute__((address_space(1))) void*)g,
      (__attribute__((address_space(3))) void*)l, 16, 0, 0);
}

__global__ __launch_bounds__(512, 2) void moe_gemm(
    const bf16_t* __restrict__ xb,    // [B, D] bf16
    const bf16_t* __restrict__ wet,   // [E, O, D] bf16
    const float* __restrict__ gates,  // [B, E]
    const float* __restrict__ be,     // [E, O]
    float* __restrict__ out)          // [B, O]
{
  // carved shared memory: ring-3 A (96K) | ring-3 B (48K) | ratios (9K) | be (4K)
  __shared__ __align__(16) char smem[160768];
  bf16_t* lA  = (bf16_t*)smem;                 // 3 x 32 KB, stride 16384 elems
  bf16_t* lB  = (bf16_t*)(smem + 147456 - 49152);  // = +98304, 3 x 16 KB
  float*  lGr = (float*)(smem + 147456);       // [256][9]: e<7 ratio g_e/g_{e+1}, [7]=g_7
  float*  lBe = (float*)(smem + 156672);       // [8][128]

  const int tid = threadIdx.x;
  const int w = tid >> 6, lane = tid & 63;

  // ---- XCD-locality remap (round 2: FETCH 533->97 MB) ----
  const int flat = blockIdx.x + (blockIdx.y << 3);  // gridDim.x == 8
  const int xcd = flat & 7, slot = flat >> 3;
  const int bt = (xcd << 2) + (slot & 3);  // b-tile 0..31
  const int ot = slot >> 2;                // o-tile 0..7
  const int b0 = bt * BM;
  const int o0 = ot * BN;

  const int m16 = lane & 15, q = lane >> 4;
  // wave -> (pair, khalf): pair p = w>>1 covers rows (p>>1)*128, cols (p&1)*64
  const int mrow = (w >> 2) << 7;          // 0 or 128
  const int ncol = ((w >> 1) & 1) << 6;    // 0 or 64
  const int kh4  = (w & 1) << 2;           // granule base of my K-half

  // ---- prologue: Horner ratios + be into LDS ----
  if (tid < 256) {
    const float4* g4 = (const float4*)(gates + (size_t)(b0 + tid) * 8);
    float4 ga = g4[0], gb = g4[1];
    float g[8] = {ga.x, ga.y, ga.z, ga.w, gb.x, gb.y, gb.z, gb.w};
    float* r = lGr + tid * 9;
#pragma unroll
    for (int e = 0; e < 7; ++e) r[e] = g[e] / g[e + 1];
    r[7] = g[7];
  } else {
    int s = tid - 256;                     // 256 threads x 4 floats = [8][128]
    const int e = s >> 5, c = (s & 31) * 4;
    float4 v = *(const float4*)(be + (size_t)e * O_SZ + o0 + c);
    float* d = lBe + e * BN + c;
    d[0] = v.x; d[1] = v.y; d[2] = v.z; d[3] = v.w;
  }

  // ---- per-lane staging constants (identical to R3) ----
  // LDS dest linear; swizzle on the GLOBAL side: phys slot s at row r holds
  // logical slot s^(r&7); reads apply the same XOR.
  const bf16_t* aptr[4]; int aoffL[4];
#pragma unroll
  for (int j = 0; j < 4; ++j) {
    int g0 = w * 64 + 512 * j;            // wave-uniform base granule
    int row = (g0 >> 3) + (lane >> 3);    // 8 granules (128B) per 64-col row
    int ls = (lane & 7) ^ (row & 7);
    aptr[j] = xb + (size_t)(b0 + row) * D_SZ + ls * 8;
    aoffL[j] = g0 * 8;
  }
  const bf16_t* bptr[2]; int boffL[2];
#pragma unroll
  for (int j = 0; j < 2; ++j) {
    int g0 = w * 64 + 512 * j;
    int row = (g0 >> 3) + (lane >> 3);
    int ls = (lane & 7) ^ (row & 7);
    bptr[j] = wet + (size_t)(o0 + row) * D_SZ + ls * 8;
    boffL[j] = g0 * 8;
  }

  // ---- hoisted per-lane LDS read byte-offsets (my K-half only) ----
  const int xk = m16 & 7;
  const int gsel = ((kh4 | q) ^ xk) << 4;
  const int offA = (mrow + m16) * 128 + gsel;
  const int offB = (ncol + m16) * 128 + gsel;

#define STAGE(t_, buf_) do {                                                   \
    const int kk_ = ((t_) & 15) << 6;                                          \
    const size_t eo_ = (((size_t)((t_) >> 4)) << 20) + kk_;                    \
    _Pragma("unroll")                                                          \
    for (int js = 0; js < 4; ++js) gl16(aptr[js] + kk_, lA + (buf_) * 16384 + aoffL[js]); \
    _Pragma("unroll")                                                          \
    for (int js = 0; js < 2; ++js) gl16(bptr[js] + eo_, lB + (buf_) * 8192 + boffL[js]); \
  } while (0)

  f32x4 acc[8][4];
#pragma unroll
  for (int i = 0; i < 8; ++i)
#pragma unroll
    for (int j = 0; j < 4; ++j) acc[i][j] = f32x4{0.f, 0.f, 0.f, 0.f};

  STAGE(0, 0);
  STAGE(1, 1);
  asm volatile("s_waitcnt lgkmcnt(0)" ::: "memory");  // publish lGr/lBe at 1st barrier

  // per step per wave: 4 B-reads + 8 A-reads -> 32 MFMA (my K=32 half)
#define BODY(cur_) do {                                                        \
    const char* la_ = (const char*)lA + (cur_) * 32768;                        \
    const char* lb_ = (const char*)lB + (cur_) * 16384;                        \
    bf16x8 a_[8], b_[4];                                                       \
    _Pragma("unroll")                                                          \
    for (int j = 0; j < 4; ++j) b_[j] = *(const bf16x8*)(lb_ + offB + j * 2048); \
    _Pragma("unroll")                                                          \
    for (int i = 0; i < 8; ++i) a_[i] = *(const bf16x8*)(la_ + offA + i * 2048); \
    __builtin_amdgcn_s_setprio(1);                                             \
    _Pragma("unroll")                                                          \
    for (int i = 0; i < 8; ++i)                                                \
      _Pragma("unroll")                                                        \
      for (int j = 0; j < 4; ++j)                                              \
        acc[i][j] = __builtin_amdgcn_mfma_f32_16x16x32_bf16(                   \
            a_[i], b_[j], acc[i][j], 0, 0, 0);                                 \
    __builtin_amdgcn_s_setprio(0);                                             \
  } while (0)

  // expert boundary: acc = (acc + be_e) * ratio_e   (even wave of each pair
  // adds be; both scale). ratio_7 slot holds g_7 (final Horner scale).
#define BOUND(e_) do {                                                         \
    float bec_[4];                                                             \
    _Pragma("unroll")                                                          \
    for (int j = 0; j < 4; ++j)                                                \
      bec_[j] = (w & 1) ? 0.f : lBe[(e_) * BN + ncol + j * 16 + m16];          \
    _Pragma("unroll")                                                          \
    for (int i = 0; i < 8; ++i) {                                              \
      _Pragma("unroll")                                                        \
      for (int rg = 0; rg < 4; ++rg) {                                         \
        float rt = lGr[(mrow + i * 16 + q * 4 + rg) * 9 + (e_)];               \
        _Pragma("unroll")                                                      \
        for (int j = 0; j < 4; ++j)                                            \
          acc[i][j][rg] = (acc[i][j][rg] + bec_[j]) * rt;                      \
      }                                                                        \
    }                                                                          \
  } while (0)

#define STEP_S(t_, cur_, nb_) do {                                             \
    asm volatile("s_waitcnt vmcnt(6)" ::: "memory");                           \
    __builtin_amdgcn_s_barrier();                                              \
    asm volatile("" ::: "memory");                                             \
    STAGE((t_) + 2, nb_);                                                      \
    BODY(cur_);                                                                \
    if (((t_) & 15) == 15) BOUND((t_) >> 4);                                   \
  } while (0)

#pragma unroll 1
  for (int t3 = 0; t3 < 126; t3 += 3) {
    STEP_S(t3 + 0, 0, 2);
    STEP_S(t3 + 1, 1, 0);
    STEP_S(t3 + 2, 2, 1);
  }
  // t = 126: no stage (tiles 0..127 all staged)
  asm volatile("s_waitcnt vmcnt(6)" ::: "memory");
  __builtin_amdgcn_s_barrier();
  asm volatile("" ::: "memory");
  BODY(0);
  // t = 127: final tile in buf 1
  asm volatile("s_waitcnt vmcnt(0)" ::: "memory");
  __builtin_amdgcn_s_barrier();
  asm volatile("" ::: "memory");
  BODY(1);
  BOUND(7);  // adds be_7 (even), scales by g_7 (both) -> acc is final partial

  // ---- pair reduction through LDS scratch (overlays ring buffers) ----
  asm volatile("s_waitcnt lgkmcnt(0)" ::: "memory");
  __builtin_amdgcn_s_barrier();
  float* scr = (float*)smem + (size_t)(w >> 1) * (128 * 65);  // 4 x 33.3 KB <= 144 KB
  if (w & 1) {
#pragma unroll
    for (int i = 0; i < 8; ++i)
#pragma unroll
      for (int rg = 0; rg < 4; ++rg) {
        float* sr = scr + (i * 16 + q * 4 + rg) * 65 + m16;
#pragma unroll
        for (int j = 0; j < 4; ++j) sr[j * 16] = acc[i][j][rg];
      }
  }
  asm volatile("s_waitcnt lgkmcnt(0)" ::: "memory");
  __builtin_amdgcn_s_barrier();
  if (!(w & 1)) {
#pragma unroll
    for (int i = 0; i < 8; ++i)
#pragma unroll
      for (int rg = 0; rg < 4; ++rg) {
        int r = i * 16 + q * 4 + rg;
        const float* sr = scr + r * 65 + m16;
        float* orow = out + (size_t)(b0 + mrow + r) * O_SZ + o0 + ncol + m16;
#pragma unroll
        for (int j = 0; j < 4; ++j) orow[j * 16] = acc[i][j][rg] + sr[j * 16];
      }
  }
}

extern "C" void kernel_launch(void* const* d_in, const int* in_sizes, int n_in,
                              void* d_out, int out_size, void* d_ws, size_t ws_size,
                              hipStream_t stream) {
  const float* x  = (const float*)d_in[0];
  const float* Wg = (const float*)d_in[1];
  const float* bg = (const float*)d_in[2];
  const float* We = (const float*)d_in[3];
  const float* be = (const float*)d_in[4];
  float* out = (float*)d_out;

  char* ws = (char*)d_ws;
  float*  gates = (float*)ws;                             // 256 KB
  bf16_t* xb    = (bf16_t*)(ws + (1 << 18));              // 16 MB
  bf16_t* wet   = (bf16_t*)(ws + (1 << 18) + (1 << 24));  // 16 MB

  prep_kernel<<<4096, 256, 0, stream>>>(x, Wg, bg, We, gates, xb, wet);
  moe_gemm<<<dim3(O_SZ / BN, B_SZ / BM), 512, 0, stream>>>(xb, wet, gates, be, out);
}